// Round 5
// baseline (259.251 us; speedup 1.0000x reference)
//
#include <hip/hip_runtime.h>
#include <hip/hip_bf16.h>

typedef __attribute__((ext_vector_type(8))) __bf16 bf16x8;
typedef __attribute__((ext_vector_type(4))) __bf16 bf16x4;
typedef __attribute__((ext_vector_type(4))) float f32x4;

#define N_NODES 50000
#define N_EDGES 800000
#define N_TILES 50000
#define TPB 25                    // tiles per block
#define N_BLOCKS 2000             // 2000 * 25 = 50000 exactly

#define XCH 1056                  // bytes per 16-float chunk slot (1024 + 32 pad)
#define XBUF_BYTES (16 * XCH)     // 16896 per tile buffer
#define H1_ROW 144                // 72 bf16 per row (16B-aligned, b128-OK)

__device__ __forceinline__ void gload_lds16(const void* g, void* l) {
    __builtin_amdgcn_global_load_lds(
        (const __attribute__((address_space(1))) void*)g,
        (__attribute__((address_space(3))) void*)l, 16, 0, 0);
}

__global__ __launch_bounds__(256, 2) void edge_mlp_kernel(
    const float* __restrict__ x_s, const float* __restrict__ x_t,
    const int* __restrict__ edge_index, const float* __restrict__ edge_attr,
    const float* __restrict__ u, const int* __restrict__ batch_e,
    const float* __restrict__ W1, const float* __restrict__ b1,
    const float* __restrict__ W2, const float* __restrict__ b2,
    float* __restrict__ out)
{
    // Total LDS: 32768 + 8192 + 2*16896 + 2*2304 = 79360 B -> 2 blocks/CU
    __shared__ __align__(16) unsigned char sW1[32768];        // [n1][k] bf16, XOR-swz
    __shared__ __align__(16) unsigned char sW2[8192];         // [n2][n1] bf16, XOR-swz
    __shared__ __align__(16) unsigned char sX[2][XBUF_BYTES]; // f32 DMA staging
    __shared__ __align__(16) unsigned char sH1[2][16 * H1_ROW];

    const int t    = threadIdx.x;
    const int wave = t >> 6;
    const int lane = t & 63;
    const int l15  = lane & 15;
    const int lk   = lane >> 4;

    // ---- stage weights as bf16 with 16B-granule XOR swizzle (T2) ----
    for (int idx = t; idx < 256 * 64; idx += 256) {
        int k = idx >> 6, n = idx & 63;
        *(__bf16*)(sW1 + n * 512 + ((k * 2) ^ ((n & 7) << 4))) = (__bf16)W1[idx];
    }
    for (int idx = t; idx < 64 * 64; idx += 256) {
        int k = idx >> 6, n = idx & 63;
        *(__bf16*)(sW2 + n * 128 + ((k * 2) ^ ((n & 7) << 4))) = (__bf16)W2[idx];
    }

    // ---- per-lane constants ----
    const int koff = wave * 16 + lk * 4;   // k-offset in each 64-seg AND this lane's n-base
    f32x4 bias1, bias2;
    #pragma unroll
    for (int r = 0; r < 4; ++r) { bias1[r] = b1[koff + r]; bias2[r] = b2[koff + r]; }

    const int tile0 = blockIdx.x * TPB;

    // ---- prologue: DMA tile0 -> buf 0 ----
    {
        const int e  = tile0 * 16 + l15;
        const int s  = edge_index[e];
        const int tg = edge_index[N_EDGES + e];
        const int bg = batch_e[e];
        unsigned char* xb = sX[0];
        gload_lds16(x_s + (long long)s * 64 + koff,        xb + (wave     ) * XCH);
        gload_lds16(x_t + (long long)tg * 64 + koff,       xb + (wave +  4) * XCH);
        gload_lds16(edge_attr + (long long)e * 64 + koff,  xb + (wave +  8) * XCH);
        gload_lds16(u + (long long)bg * 64 + koff,         xb + (wave + 12) * XCH);
    }
    __syncthreads();   // full drain once: weights + buf0 ready

    const int w1row = (wave * 16 + l15) * 512;
    const int w2row = (wave * 16 + l15) * 128;
    const int wxor  = (l15 & 7) << 4;

    for (int i = 0; i < TPB; ++i) {
        const int tile = tile0 + i;
        unsigned char* xcur = sX[i & 1];
        unsigned char* hcur = sH1[i & 1];

        // ---- issue next tile's DMA, then counted-vmcnt drain of current ----
        if (i + 1 < TPB) {
            const int e1  = (tile + 1) * 16 + l15;
            const int s1  = edge_index[e1];
            const int tg1 = edge_index[N_EDGES + e1];
            const int bg1 = batch_e[e1];
            unsigned char* xn = sX[(i + 1) & 1];
            gload_lds16(x_s + (long long)s1 * 64 + koff,        xn + (wave     ) * XCH);
            gload_lds16(x_t + (long long)tg1 * 64 + koff,       xn + (wave +  4) * XCH);
            gload_lds16(edge_attr + (long long)e1 * 64 + koff,  xn + (wave +  8) * XCH);
            gload_lds16(u + (long long)bg1 * 64 + koff,         xn + (wave + 12) * XCH);
            asm volatile("s_waitcnt vmcnt(4)" ::: "memory");   // drain tile i, keep i+1 in flight
        } else {
            asm volatile("s_waitcnt vmcnt(0)" ::: "memory");
        }
        __builtin_amdgcn_s_barrier();
        __builtin_amdgcn_sched_barrier(0);

        // ---- GEMM1^T: H1^T[16 n1 x 16 e] = W1^T-frag x X-frag, this wave's quadrant ----
        f32x4 acc = bias1;
        const unsigned char* xbase = xcur + (2 * (lk & 1)) * 256 + l15 * 16;
        #pragma unroll
        for (int kk = 0; kk < 8; ++kk) {
            const unsigned char* xp = xbase + (kk * 2 + (lk >> 1)) * XCH;
            f32x4 v0 = *(const f32x4*)xp;          // k = kk*32+lk*8 + 0..3 (f32)
            f32x4 v1 = *(const f32x4*)(xp + 256);  // k + 4..7
            bf16x8 xa;
            xa[0] = (__bf16)v0[0]; xa[1] = (__bf16)v0[1];
            xa[2] = (__bf16)v0[2]; xa[3] = (__bf16)v0[3];
            xa[4] = (__bf16)v1[0]; xa[5] = (__bf16)v1[1];
            xa[6] = (__bf16)v1[2]; xa[7] = (__bf16)v1[3];
            bf16x8 af = *(const bf16x8*)(sW1 + w1row + ((kk * 64 + lk * 16) ^ wxor));
            acc = __builtin_amdgcn_mfma_f32_16x16x32_bf16(af, xa, acc, 0, 0, 0);
        }

        // ---- LeakyReLU(0.1) -> bf16 -> sH1[edge][n1] (b64 write) ----
        bf16x4 pk;
        #pragma unroll
        for (int r = 0; r < 4; ++r) {
            float v = acc[r];
            v = fmaxf(v, 0.1f * v);               // == LeakyReLU(0.1) for all v
            pk[r] = (__bf16)v;
        }
        *(bf16x4*)(hcur + l15 * H1_ROW + koff * 2) = pk;
        asm volatile("s_waitcnt lgkmcnt(0)" ::: "memory");
        __builtin_amdgcn_s_barrier();
        __builtin_amdgcn_sched_barrier(0);

        // ---- GEMM2^T: O^T[16 n2 x 16 e] = W2^T-frag x H1-frag ----
        f32x4 acc2 = bias2;
        #pragma unroll
        for (int kk2 = 0; kk2 < 2; ++kk2) {
            bf16x8 bh = *(const bf16x8*)(hcur + l15 * H1_ROW + kk2 * 64 + lk * 16);
            bf16x8 aw = *(const bf16x8*)(sW2 + w2row + ((kk2 * 64 + lk * 16) ^ wxor));
            acc2 = __builtin_amdgcn_mfma_f32_16x16x32_bf16(aw, bh, acc2, 0, 0, 0);
        }

        // ---- store: lane holds out[e][koff..koff+3] -> float4 ----
        *(f32x4*)(out + (long long)(tile * 16 + l15) * 64 + koff) = acc2;
    }
}

extern "C" void kernel_launch(void* const* d_in, const int* in_sizes, int n_in,
                              void* d_out, int out_size, void* d_ws, size_t ws_size,
                              hipStream_t stream) {
    const float* x_s        = (const float*)d_in[0];
    const float* x_t        = (const float*)d_in[1];
    const int*   edge_index = (const int*)d_in[2];   // harness: integer -> int32
    const float* edge_attr  = (const float*)d_in[3];
    const float* u          = (const float*)d_in[4];
    const int*   batch_e    = (const int*)d_in[5];
    const float* W1         = (const float*)d_in[6];
    const float* b1         = (const float*)d_in[7];
    const float* W2         = (const float*)d_in[8];
    const float* b2         = (const float*)d_in[9];
    float*       out        = (float*)d_out;

    edge_mlp_kernel<<<N_BLOCKS, 256, 0, stream>>>(
        x_s, x_t, edge_index, edge_attr, u, batch_e, W1, b1, W2, b2, out);
}

// Round 7
// 165.166 us; speedup vs baseline: 1.5696x; 1.5696x over previous
//
#include <hip/hip_runtime.h>
#include <hip/hip_bf16.h>

typedef __attribute__((ext_vector_type(8))) __bf16 bf16x8;
typedef __attribute__((ext_vector_type(4))) float f32x4;

#define N_NODES 50000
#define N_EDGES 800000
#define N_TILES 50000            // 16-edge tiles
#define WAVES 8                  // 512-thread blocks
#define TPW 4
#define TILES_PER_BLOCK (WAVES * TPW)   // 32

__global__ __launch_bounds__(512, 4) void edge_mlp_kernel(
    const float* __restrict__ x_s, const float* __restrict__ x_t,
    const int* __restrict__ edge_index, const float* __restrict__ edge_attr,
    const float* __restrict__ u, const int* __restrict__ batch_e,
    const float* __restrict__ W1, const float* __restrict__ b1,
    const float* __restrict__ W2, const float* __restrict__ b2,
    float* __restrict__ out)
{
    // LDS: 32768 + 8192 + 8*2432 = 60416 B -> 2 blocks/CU -> 16 waves/CU
    __shared__ __align__(16) unsigned char sW1[32768];   // [n1][k] bf16, 512B rows, XOR-swz (r5-verified)
    __shared__ __align__(16) unsigned char sW2[8192];    // [n2][n1] bf16, 128B rows, XOR-swz (r5-verified)
    __shared__ __align__(16) __bf16 sH1[WAVES][16][76];  // [edge][n1], pad 76 (r4-verified)

    const int t = threadIdx.x;

    // ---- stage weights bf16, XOR-swizzled ----
    for (int idx = t; idx < 256 * 64; idx += 512) {
        int k = idx >> 6, n = idx & 63;
        *(__bf16*)(sW1 + n * 512 + ((k * 2) ^ ((n & 7) << 4))) = (__bf16)W1[idx];
    }
    for (int idx = t; idx < 64 * 64; idx += 512) {
        int k = idx >> 6, n = idx & 63;
        *(__bf16*)(sW2 + n * 128 + ((k * 2) ^ ((n & 7) << 4))) = (__bf16)W2[idx];
    }
    __syncthreads();

    const int wave = t >> 6;
    const int lane = t & 63;
    const int l15  = lane & 15;
    const int lk   = lane >> 4;
    const int wxor = (l15 & 7) << 4;

    // ---- bias registers (r4-verified) ----
    float bv1[4];
    #pragma unroll
    for (int nf = 0; nf < 4; ++nf) bv1[nf] = b1[nf * 16 + l15];
    f32x4 bias2frag[4];
    #pragma unroll
    for (int mf = 0; mf < 4; ++mf)
        #pragma unroll
        for (int r = 0; r < 4; ++r)
            bias2frag[mf][r] = b2[mf * 16 + lk * 4 + r];

    const int tile_base = (blockIdx.x * WAVES + wave) * TPW;

    // ---- preload indices for this wave's tiles (guarded) ----
    int srcs[TPW], tgts[TPW], bgs[TPW];
    #pragma unroll
    for (int i = 0; i < TPW; ++i) {
        const int tile = tile_base + i;
        if (tile < N_TILES) {
            const int e = tile * 16 + l15;
            srcs[i] = edge_index[e];
            tgts[i] = edge_index[N_EDGES + e];
            bgs[i]  = batch_e[e];
        } else { srcs[i] = 0; tgts[i] = 0; bgs[i] = 0; }
    }

    for (int i = 0; i < TPW; ++i) {
        const int tile = tile_base + i;
        if (tile >= N_TILES) break;
        const int e = tile * 16 + l15;

        const float* seg0 = x_s + (long long)srcs[i] * 64;
        const float* seg1 = x_t + (long long)tgts[i] * 64;
        const float* seg2 = edge_attr + (long long)e * 64;
        const float* seg3 = u + (long long)bgs[i] * 64;

        // ---- GEMM1 (r2 structure): gather -> cvt -> MFMA, bias folded ----
        f32x4 acc[4];
        #pragma unroll
        for (int nf = 0; nf < 4; ++nf)
            acc[nf] = (f32x4){bv1[nf], bv1[nf], bv1[nf], bv1[nf]};
        #pragma unroll
        for (int kk = 0; kk < 8; ++kk) {
            const int k0 = kk * 32 + lk * 8;
            const float* p =
                (k0 < 64)  ? (seg0 + k0) :
                (k0 < 128) ? (seg1 + (k0 - 64)) :
                (k0 < 192) ? (seg2 + (k0 - 128)) :
                             (seg3 + (k0 - 192));
            float4 f0 = *(const float4*)p;
            float4 f1 = *(const float4*)(p + 4);
            bf16x8 a;
            a[0] = (__bf16)f0.x; a[1] = (__bf16)f0.y;
            a[2] = (__bf16)f0.z; a[3] = (__bf16)f0.w;
            a[4] = (__bf16)f1.x; a[5] = (__bf16)f1.y;
            a[6] = (__bf16)f1.z; a[7] = (__bf16)f1.w;
            #pragma unroll
            for (int nf = 0; nf < 4; ++nf) {
                bf16x8 b = *(const bf16x8*)(sW1 + (nf * 16 + l15) * 512 +
                                            ((kk * 64 + lk * 16) ^ wxor));
                acc[nf] = __builtin_amdgcn_mfma_f32_16x16x32_bf16(a, b, acc[nf], 0, 0, 0);
            }
        }

        // ---- LeakyReLU(0.1) -> bf16 -> sH1 (D: row=lk*4+r, col=nf*16+l15) ----
        #pragma unroll
        for (int nf = 0; nf < 4; ++nf)
            #pragma unroll
            for (int r = 0; r < 4; ++r) {
                float v = acc[nf][r];
                v = fmaxf(v, 0.1f * v);
                sH1[wave][lk * 4 + r][nf * 16 + l15] = (__bf16)v;
            }
        // same-wave LDS RAW: compiler inserts lgkmcnt wait

        // ---- GEMM2^T: O^T = W2^T x H1^T (r4-verified) ----
        f32x4 acc2[4];
        #pragma unroll
        for (int mf = 0; mf < 4; ++mf) acc2[mf] = bias2frag[mf];
        #pragma unroll
        for (int kk2 = 0; kk2 < 2; ++kk2) {
            bf16x8 bh = *(const bf16x8*)&sH1[wave][l15][kk2 * 32 + lk * 8];
            #pragma unroll
            for (int mf = 0; mf < 4; ++mf) {
                bf16x8 aw = *(const bf16x8*)(sW2 + (mf * 16 + l15) * 128 +
                                             ((kk2 * 64 + lk * 16) ^ wxor));
                acc2[mf] = __builtin_amdgcn_mfma_f32_16x16x32_bf16(aw, bh, acc2[mf], 0, 0, 0);
            }
        }

        // ---- store: lane holds out[e][mf*16+lk*4 .. +3] -> 4x float4 ----
        float* orow = out + (long long)e * 64;
        #pragma unroll
        for (int mf = 0; mf < 4; ++mf)
            *(f32x4*)&orow[mf * 16 + lk * 4] = acc2[mf];
    }
}

extern "C" void kernel_launch(void* const* d_in, const int* in_sizes, int n_in,
                              void* d_out, int out_size, void* d_ws, size_t ws_size,
                              hipStream_t stream) {
    const float* x_s        = (const float*)d_in[0];
    const float* x_t        = (const float*)d_in[1];
    const int*   edge_index = (const int*)d_in[2];   // harness: integer -> int32
    const float* edge_attr  = (const float*)d_in[3];
    const float* u          = (const float*)d_in[4];
    const int*   batch_e    = (const int*)d_in[5];
    const float* W1         = (const float*)d_in[6];
    const float* b1         = (const float*)d_in[7];
    const float* W2         = (const float*)d_in[8];
    const float* b2         = (const float*)d_in[9];
    float*       out        = (float*)d_out;

    const int nblocks = (N_TILES + TILES_PER_BLOCK - 1) / TILES_PER_BLOCK; // 1563
    edge_mlp_kernel<<<nblocks, 512, 0, stream>>>(
        x_s, x_t, edge_index, edge_attr, u, batch_e, W1, b1, W2, b2, out);
}